// Round 8
// baseline (128.420 us; speedup 1.0000x reference)
//
#include <hip/hip_runtime.h>

#define NPTS 8192
#define NTOT 16384
#define KNB 11
#define CAP 16
#define MARG 9.0f
#define QMAX 2048
#define NTILE 1056

typedef __attribute__((ext_vector_type(8))) short short8;
typedef __attribute__((ext_vector_type(4))) float f32x4;

// ---- persistent control state (module .bss = zero on load; the finale
// re-zeroes everything for the next launch/replay, so no memset dispatch) ----
__device__ unsigned g_ticket;       // producer work tickets
__device__ int g_flags[256];        // per-chunk "encoded" flags
__device__ unsigned g_done[260];    // 8 striped arrival ctrs (j*32) + level2 [256]
__device__ int g_lctr;              // coupled-list counter
__device__ unsigned g_cnt[NTOT];    // per-row candidate counters

__device__ __forceinline__ unsigned short f2bf(float x) {
  union { float f; unsigned u; } v; v.f = x;
  unsigned r = v.u + 0x7FFFu + ((v.u >> 16) & 1u);
  return (unsigned short)(r >> 16);
}

__device__ __forceinline__ float sigm(float x) { return 1.f / (1.f + expf(-x)); }

// Agent-scope coherent helpers. Producers WRITE-THROUGH so gated consumers'
// plain reads (first touch after the gate) fetch correct data from the
// coherence point; no stale local-L2 copy can exist (kernel-start invalidate).
__device__ __forceinline__ void st_cg4u(unsigned* p, unsigned v) {
  __hip_atomic_store(p, v, __ATOMIC_RELAXED, __HIP_MEMORY_SCOPE_AGENT);
}
__device__ __forceinline__ void st_cg4f(float* p, float v) {
  union { float f; unsigned u; } c; c.f = v;
  __hip_atomic_store((unsigned*)p, c.u, __ATOMIC_RELAXED, __HIP_MEMORY_SCOPE_AGENT);
}
__device__ __forceinline__ void st_cg8(unsigned long long* p, unsigned long long v) {
  __hip_atomic_store(p, v, __ATOMIC_RELAXED, __HIP_MEMORY_SCOPE_AGENT);
}
__device__ __forceinline__ unsigned ld_cg4u(const unsigned* p) {
  return __hip_atomic_load(p, __ATOMIC_RELAXED, __HIP_MEMORY_SCOPE_AGENT);
}
__device__ __forceinline__ int ld_cg4i(const int* p) {
  return __hip_atomic_load(p, __ATOMIC_RELAXED, __HIP_MEMORY_SCOPE_AGENT);
}

// LDS union across the three roles a block can play (max ~34 KB -> 4 blocks/CU).
union SMF {
  struct { float sp[64 * 64]; float st[64 * 65]; float sPart[4][64]; } a; // encode
  uint4 sB[1024];                                                        // Gram panel
  struct { float qs[QMAX]; float su[QMAX]; int sl[QMAX]; } c;            // finale
};

// ONE fused kernel, 1056 blocks x 256 threads.
// Ticket < 256: encode chunk (64 points) with coherent stores, set flag.
// All blocks: Gram tile bid, gated on the 8 producer chunks it reads.
// Striped arrival; globally-last block runs the coupled-subgraph finale + resets.
__global__ __launch_bounds__(256) void fuse(
    const float* __restrict__ p, const float* __restrict__ W1,
    const float* __restrict__ b1, const float* __restrict__ W2,
    const float* __restrict__ b2, const float* __restrict__ logits,
    float* __restrict__ out,
    float* __restrict__ f32f, unsigned short* __restrict__ fpre,
    float* __restrict__ sq, float* __restrict__ sq32,
    unsigned* __restrict__ cand, int* __restrict__ list,
    int* __restrict__ rowmap, float* __restrict__ Wbuf, int* __restrict__ IDXs) {
  __shared__ SMF sm;
  __shared__ int stk;
  __shared__ int slast;
  int t = threadIdx.x;
  int bid = blockIdx.x;

  if (t == 0) stk = (int)atomicAdd(&g_ticket, 1u);
  __syncthreads();
  int tk = stk;

  // ================= producer: encode chunk tk =================
  if (tk < 256) {
    int lane = t & 63;
    int w = __builtin_amdgcn_readfirstlane(t >> 6);
    int e0 = w * 16;                        // wave-uniform -> scalar W loads
    int base = tk * 64;
    int b = base >> 13, n0 = base & (NPTS - 1);
    const float* pb = p + (size_t)b * 64 * NPTS + n0;

    // stage p tile: 64 d-rows x 64 points, coalesced uint4
    int row = t >> 4, chunk = t & 15;
#pragma unroll
    for (int k = 0; k < 4; ++k) {
      int r = k * 16 + row;
      uint4 v = *(const uint4*)(pb + (size_t)r * NPTS + chunk * 4);
      *(uint4*)(sm.a.sp + r * 64 + chunk * 4) = v;
    }
    __syncthreads();

    // GEMM1: t[n][e] = b1[e] + sum_d p[d][n]*W1[d][e]
    float tt[16];
#pragma unroll
    for (int j = 0; j < 16; ++j) tt[j] = b1[e0 + j];
#pragma unroll 8
    for (int d = 0; d < 64; ++d) {
      float pd = sm.a.sp[d * 64 + lane];
#pragma unroll
      for (int j = 0; j < 16; ++j)
        tt[j] = fmaf(pd, W1[d * 64 + e0 + j], tt[j]);
    }
#pragma unroll
    for (int j = 0; j < 16; ++j) sm.a.st[lane * 65 + e0 + j] = tt[j];
    __syncthreads();

    // GEMM2: f[n][e] = b2[e] + sum_d t[n][d]*W2[d][e]
    float f[16];
#pragma unroll
    for (int j = 0; j < 16; ++j) f[j] = b2[e0 + j];
#pragma unroll 8
    for (int d = 0; d < 64; ++d) {
      float td = sm.a.st[lane * 65 + d];
#pragma unroll
      for (int j = 0; j < 16; ++j)
        f[j] = fmaf(td, W2[d * 64 + e0 + j], f[j]);
    }

    float s = 0.f;
#pragma unroll
    for (int j = 0; j < 16; ++j) s = fmaf(f[j], f[j], s);
    sm.a.sPart[w][lane] = s;
    __syncthreads();
    if (w == 0) {
      float s32 = sm.a.sPart[0][lane] + sm.a.sPart[1][lane];
      float s64 = s32 + (sm.a.sPart[2][lane] + sm.a.sPart[3][lane]);
      st_cg4f(&sq32[base + lane], s32);
      st_cg4f(&sq[base + lane], s64);
      float lg = logits[base + lane];       // decoupled fast path for ALL rows
      float u = lg;
#pragma unroll
      for (int it = 0; it < 5; ++it) u = lg - sigm(u);
      st_cg4f(&out[base + lane], sigm(u));  // finale overwrites coupled rows
    }

    // f32f: 16 floats -> 8x 8B coherent stores
    unsigned long long* o8 =
        (unsigned long long*)(f32f + (size_t)(base + lane) * 64 + e0);
#pragma unroll
    for (int jj = 0; jj < 8; ++jj) {
      union { float f; unsigned u; } lo, hi;
      lo.f = f[2 * jj]; hi.f = f[2 * jj + 1];
      st_cg8(&o8[jj], (unsigned long long)lo.u |
                      ((unsigned long long)hi.u << 32));
    }
    if (w < 2) {                            // dims 0..31 -> bf16 prefilter
      unsigned long long* ob =
          (unsigned long long*)(fpre + (size_t)(base + lane) * 32 + e0);
#pragma unroll
      for (int jj = 0; jj < 4; ++jj) {
        unsigned w0 = (unsigned)f2bf(f[4 * jj]) |
                      ((unsigned)f2bf(f[4 * jj + 1]) << 16);
        unsigned w1 = (unsigned)f2bf(f[4 * jj + 2]) |
                      ((unsigned)f2bf(f[4 * jj + 3]) << 16);
        st_cg8(&ob[jj], (unsigned long long)w0 |
                        ((unsigned long long)w1 << 32));
      }
    }
    asm volatile("s_waitcnt vmcnt(0)" ::: "memory");  // per-wave drain
    __syncthreads();                                  // all waves drained
    if (t == 0)
      __hip_atomic_store(&g_flags[tk], 1, __ATOMIC_RELAXED,
                         __HIP_MEMORY_SCOPE_AGENT);
  }

  // ================= tile geometry =================
  int b = (bid >= 528) ? 1 : 0;
  int rem = bid - b * 528;
  int band = (int)((sqrtf(8.f * (float)rem + 1.f) - 1.f) * 0.5f);
  if (((band + 1) * (band + 2)) / 2 <= rem) band++;
  else if ((band * (band + 1)) / 2 > rem) band--;
  int seg = rem - (band * (band + 1)) / 2;

  // ================= gate: the 8 producer chunks this tile reads =================
  {
    int c0 = b * 128 + band * 4, c1 = b * 128 + seg * 4;
    if (t == 0) {
      for (long it2 = 0; it2 < 100000000L; ++it2) {
        int ok = ld_cg4i(&g_flags[c0]) & ld_cg4i(&g_flags[c0 + 1]) &
                 ld_cg4i(&g_flags[c0 + 2]) & ld_cg4i(&g_flags[c0 + 3]) &
                 ld_cg4i(&g_flags[c1]) & ld_cg4i(&g_flags[c1 + 1]) &
                 ld_cg4i(&g_flags[c1 + 2]) & ld_cg4i(&g_flags[c1 + 3]);
        if (ok) break;
        __builtin_amdgcn_s_sleep(1);
      }
    }
    __syncthreads();
  }

  // ================= phase B: one Gram tile (R6-validated math) =================
  {
    int lane = t & 63;
    int arow = lane & 15;
    int q = lane >> 4;
    int wave = t >> 6;
    int rowbase = band * 256 + wave * 64;
    int cbase = seg * 256;
    const unsigned short* fb = fpre + (size_t)b * NPTS * 32;
    const float* s32b = sq32 + b * NPTS;

    const uint4* gsrc = (const uint4*)fb + (size_t)seg * 1024;
    uint4 v[4];
#pragma unroll
    for (int k = 0; k < 4; ++k) v[k] = gsrc[t + k * 256];

    short8 afrag[4];
#pragma unroll
    for (int tr = 0; tr < 4; ++tr)
      afrag[tr] = *(const short8*)(fb + (size_t)(rowbase + tr * 16 + arow) * 32 + q * 8);

    f32x4 srq[4], nh[4];                    // nh = -0.5*sq_row -> MFMA C operand
#pragma unroll
    for (int tr = 0; tr < 4; ++tr) {
      srq[tr] = *(const f32x4*)(s32b + rowbase + tr * 16 + (q << 2));
      nh[tr] = -0.5f * srq[tr];
    }
    float thrc[16];                         // per-lane column threshold
#pragma unroll
    for (int cc = 0; cc < 4; ++cc)
#pragma unroll
      for (int tc = 0; tc < 4; ++tc)
        thrc[cc * 4 + tc] = 0.5f * s32b[cbase + cc * 64 + tc * 16 + arow] - 0.5f * MARG;

    __syncthreads();                        // producer-phase LDS readers done
#pragma unroll
    for (int k = 0; k < 4; ++k) {
      int c = t + k * 256;
      int r = c >> 2, qq = c & 3;
      sm.sB[r * 4 + (qq ^ (r & 3))] = v[k];
    }
    __syncthreads();

    unsigned hitmask = 0u;
#pragma unroll
    for (int cc = 0; cc < 4; ++cc)
#pragma unroll
      for (int tc = 0; tc < 4; ++tc) {
        int e = cc * 4 + tc;
        int rl = cc * 64 + tc * 16 + arow;
        short8 bf = *(const short8*)&sm.sB[rl * 4 + (q ^ (rl & 3))];
        f32x4 a0 = __builtin_amdgcn_mfma_f32_16x16x32_bf16(afrag[0], bf, nh[0], 0, 0, 0);
        f32x4 a1 = __builtin_amdgcn_mfma_f32_16x16x32_bf16(afrag[1], bf, nh[1], 0, 0, 0);
        f32x4 a2 = __builtin_amdgcn_mfma_f32_16x16x32_bf16(afrag[2], bf, nh[2], 0, 0, 0);
        f32x4 a3 = __builtin_amdgcn_mfma_f32_16x16x32_bf16(afrag[3], bf, nh[3], 0, 0, 0);
        float m0 = fmaxf(fmaxf(a0[0], a0[1]), fmaxf(a0[2], a0[3]));
        float m1 = fmaxf(fmaxf(a1[0], a1[1]), fmaxf(a1[2], a1[3]));
        float m2 = fmaxf(fmaxf(a2[0], a2[1]), fmaxf(a2[2], a2[3]));
        float m3 = fmaxf(fmaxf(a3[0], a3[1]), fmaxf(a3[2], a3[3]));
        float m = fmaxf(fmaxf(m0, m1), fmaxf(m2, m3));
        if (__ballot(m > thrc[e])) hitmask |= (1u << e);
      }

    if (hitmask) {
#pragma unroll 1
      for (int e = 0; e < 16; ++e) {
        if (!(hitmask & (1u << e))) continue;
        int cc = e >> 2, tc = e & 3;
        int rl = cc * 64 + tc * 16 + arow;
        short8 bf = *(const short8*)&sm.sB[rl * 4 + (q ^ (rl & 3))];
        int colpt = cbase + cc * 64 + tc * 16 + arow;
        float scv = s32b[colpt];
        f32x4 acc[4];
#pragma unroll
        for (int tr = 0; tr < 4; ++tr)
          acc[tr] = __builtin_amdgcn_mfma_f32_16x16x32_bf16(afrag[tr], bf, nh[tr], 0, 0, 0);
#pragma unroll
        for (int tr = 0; tr < 4; ++tr)
#pragma unroll
          for (int rg = 0; rg < 4; ++rg) {
            float d2 = scv - 2.f * acc[tr][rg];    // = sq_row + sq_col - 2*dot
            if (d2 < MARG) {
              int rowpt = rowbase + tr * 16 + (q << 2) + rg;
              int gr = b * NPTS + rowpt;
              union { float f; unsigned u; } cv; cv.f = d2 + 16.f;  // monotone bits
              unsigned kb = cv.u & 0xFFFFE000u;
              unsigned slot = atomicAdd(&g_cnt[gr], 1u);
              if (slot < CAP) st_cg4u(&cand[gr * CAP + slot], kb | (unsigned)colpt);
              if (slot == 1u) {               // 1->2 transition: row becomes coupled
                int ls = atomicAdd(&g_lctr, 1);
                if (ls < QMAX * 4) __hip_atomic_store(&list[ls], gr, __ATOMIC_RELAXED,
                                                      __HIP_MEMORY_SCOPE_AGENT);
              }
              if (band != seg) {
                int gc = b * NPTS + colpt;
                unsigned slot2 = atomicAdd(&g_cnt[gc], 1u);
                if (slot2 < CAP) st_cg4u(&cand[gc * CAP + slot2], kb | (unsigned)rowpt);
                if (slot2 == 1u) {
                  int ls2 = atomicAdd(&g_lctr, 1);
                  if (ls2 < QMAX * 4) __hip_atomic_store(&list[ls2], gc, __ATOMIC_RELAXED,
                                                         __HIP_MEMORY_SCOPE_AGENT);
                }
              }
            }
          }
      }
    }
  }

  // ================= arrival: striped, fence-free =================
  asm volatile("s_waitcnt vmcnt(0)" ::: "memory");   // per-wave drain
  __syncthreads();                                   // all waves drained
  if (t == 0) {
    int last = 0;
    unsigned o = atomicAdd(&g_done[(bid & 7) * 32], 1u);
    if (o == 131u) {                         // stripe of 132 complete
      unsigned o2 = atomicAdd(&g_done[256], 1u);
      if (o2 == 7u) last = 1;                // globally last block out
    }
    slast = last;
  }
  __syncthreads();
  if (!slast) return;

  // ================= finale (last block): coupled subgraph =================
  int nm = ld_cg4i(&g_lctr); if (nm > QMAX) nm = QMAX;

#pragma unroll 1
  for (int k = t; k < nm; k += 256) {
    int r = ld_cg4i(&list[k]);
    sm.c.sl[k] = r;
    rowmap[r] = k;                          // every captured neighbor is coupled
    sm.c.qs[k] = sigm(logits[r]);
  }
  __syncthreads();

#pragma unroll 1
  for (int k = t; k < nm; k += 256) {
    int r = sm.c.sl[k];
    int bb = r >> 13;
    unsigned count = ld_cg4u(&g_cnt[r]);
    if (count > CAP) count = CAP;

    unsigned kc[CAP];
#pragma unroll
    for (int j = 0; j < CAP; ++j)
      kc[j] = (j < (int)count) ? ld_cg4u(&cand[r * CAP + j]) : 0xFFFFFFFFu;
#pragma unroll
    for (int a = 0; a < CAP - 1; ++a)
#pragma unroll
      for (int c = 0; c < CAP - 1; ++c) {
        unsigned lo = min(kc[c], kc[c + 1]);
        unsigned hi = max(kc[c], kc[c + 1]);
        kc[c] = lo; kc[c + 1] = hi;
      }

    float fr[64];
    const f32x4* fr4 = (const f32x4*)(f32f + (size_t)r * 64);
#pragma unroll
    for (int j = 0; j < 16; ++j) {
      f32x4 v = fr4[j];
      fr[4 * j] = v[0]; fr[4 * j + 1] = v[1]; fr[4 * j + 2] = v[2]; fr[4 * j + 3] = v[3];
    }
    float sqr = sq[r];
    int nsel = (int)count < KNB ? (int)count : KNB;
#pragma unroll
    for (int kk = 0; kk < KNB; ++kk) {
      float wgt = 0.f;
      int gi = r;
      if (kk < nsel) {
        int col = (int)(kc[kk] & 8191u);
        gi = bb * NPTS + col;
        const float* fm = f32f + (size_t)gi * 64;
        float dot = 0.f;
#pragma unroll
        for (int d = 0; d < 64; ++d) dot = fmaf(fr[d], fm[d], dot); // matches sq chain
        float d2 = sqr + sq[gi] - 2.f * dot;
        wgt = expf(-d2);
      }
      Wbuf[k * KNB + kk] = wgt;
      IDXs[k * KNB + kk] = rowmap[gi] & (QMAX - 1);
    }
  }
  __syncthreads();

  for (int it = 0; it < 5; ++it) {
#pragma unroll 1
    for (int k = t; k < nm; k += 256) {
      float msg = 0.f;
      const float* wp = Wbuf + k * KNB;
      const int* ip = IDXs + k * KNB;
#pragma unroll
      for (int kk = 0; kk < KNB; ++kk) msg = fmaf(wp[kk], sm.c.qs[ip[kk]], msg);
      sm.c.su[k] = logits[sm.c.sl[k]] - msg;
    }
    __syncthreads();
#pragma unroll 1
    for (int k = t; k < nm; k += 256) sm.c.qs[k] = sigm(sm.c.su[k]);
    __syncthreads();
  }
#pragma unroll 1
  for (int k = t; k < nm; k += 256) st_cg4f(&out[sm.c.sl[k]], sigm(sm.c.su[k]));

  // ---- reset persistent control state for the next launch/replay ----
  // GRID-STRIDE over ALL entries: the R7 bug was `if (t < 260)` with only 256
  // threads -> g_done[256] (level-2 counter) never reset -> finale never ran
  // on replay 2 -> state never recycled -> replays 3+ ran with no producers.
#pragma unroll 1
  for (int k = t; k < NTOT; k += 256) g_cnt[k] = 0u;
#pragma unroll 1
  for (int k = t; k < 260; k += 256) g_done[k] = 0u;   // includes g_done[256]
  if (t < 256) g_flags[t] = 0;
  if (t == 0) { g_lctr = 0; g_ticket = 0u; }
}

// ---------------- launch ----------------
extern "C" void kernel_launch(void* const* d_in, const int* in_sizes, int n_in,
                              void* d_out, int out_size, void* d_ws, size_t ws_size,
                              hipStream_t stream) {
  const float* logits = (const float*)d_in[0]; // [2][8192]
  const float* p      = (const float*)d_in[1]; // [2][64][8192]
  const float* W1     = (const float*)d_in[2];
  const float* b1     = (const float*)d_in[3];
  const float* W2     = (const float*)d_in[4];
  const float* b2     = (const float*)d_in[5];
  float* out = (float*)d_out;                  // [2][8192]

  char* ws = (char*)d_ws;
  float* f32f = (float*)ws;                                        // NTOT*64 f
  unsigned short* fpre = (unsigned short*)(f32f + (size_t)NTOT * 64); // NTOT*32 bf16
  float* sq = (float*)(fpre + (size_t)NTOT * 32);                  // NTOT f
  float* sq32 = sq + NTOT;                                         // NTOT f
  unsigned* cand = (unsigned*)(sq32 + NTOT);                       // NTOT*CAP u32
  int* list = (int*)(cand + (size_t)NTOT * CAP);                   // QMAX*4 i32
  int* rowmap = list + QMAX * 4;                                   // NTOT i32
  float* Wbuf = (float*)(rowmap + NTOT);                           // QMAX*KNB f
  int* IDXs = (int*)(Wbuf + (size_t)QMAX * KNB);                   // QMAX*KNB i32

  fuse<<<NTILE, 256, 0, stream>>>(p, W1, b1, W2, b2, logits, out,
                                  f32f, fpre, sq, sq32, cand, list,
                                  rowmap, Wbuf, IDXs);
}

// Round 9
// 107.974 us; speedup vs baseline: 1.1894x; 1.1894x over previous
//
#include <hip/hip_runtime.h>

#define NPTS 8192
#define NTOT 16384
#define KNB 11
#define CAP 16
#define MARG 9.0f
#define MAXM 8192
#define QMAX 2048              // finale slots (observed coupled rows ~300)

typedef __attribute__((ext_vector_type(8))) short short8;
typedef __attribute__((ext_vector_type(4))) float f32x4;

__device__ __forceinline__ unsigned short f2bf(float x) {
  union { float f; unsigned u; } v; v.f = x;
  unsigned r = v.u + 0x7FFFu + ((v.u >> 16) & 1u);
  return (unsigned short)(r >> 16);
}

__device__ __forceinline__ float sigm(float x) { return 1.f / (1.f + expf(-x)); }

// ---------------- K1: encode (512 thr = 2 waves/SIMD) + decoupled out ----------------
// f = (p^T*W1 + b1)*W2 + b2 ; sq/sq32 ; bf16 prefilter. 256 blocks x 512 threads:
// 64 points/block, 8 waves, wave w handles dims e0=w*8 (wave-uniform -> s_load).
// At 256 blocks x 4 waves the old k1 had 1 wave/SIMD (zero latency hiding);
// 8 waves/block gives 2/SIMD. Per-dim FMA chains unchanged -> f bit-identical.
// Also: writes out[r] = decoupled 5-iter result for ALL rows (validated R6/R8);
// k3's finale overwrites the ~300 coupled rows. Zeroes cnt/lctr.
__global__ __launch_bounds__(512) void k1_encode(
    const float* __restrict__ p,      // [2][64][NPTS]
    const float* __restrict__ W1,     // [64][64]
    const float* __restrict__ b1,     // [64]
    const float* __restrict__ W2,     // [64][64]
    const float* __restrict__ b2,     // [64]
    const float* __restrict__ logits, // [NTOT]
    float* __restrict__ out,          // [NTOT]
    float* __restrict__ f32f,         // [NTOT][64]
    unsigned short* __restrict__ fpre,// [NTOT][32] bf16 (dims 0..31)
    float* __restrict__ sq,           // [NTOT]
    float* __restrict__ sq32,         // [NTOT]
    unsigned* __restrict__ cnt,       // [NTOT] (zeroed here)
    int* __restrict__ lctr) {         // coupled-list counter (zeroed here)
  __shared__ float sp[64 * 64];       // 16 KB: sp[d*64 + n_local]
  __shared__ float st[64 * 65];       // 16.25 KB: st[n_local*65 + d] (+1 pad)
  __shared__ float sPart[8][64];
  int t = threadIdx.x, lane = t & 63;
  int w = __builtin_amdgcn_readfirstlane(t >> 6);  // 0..7
  int e0 = w * 8;                           // wave-uniform -> scalar W loads
  int base = blockIdx.x * 64;
  int b = base >> 13, n0 = base & (NPTS - 1);
  const float* pb = p + (size_t)b * 64 * NPTS + n0;

  if (t < 64) {
    cnt[base + t] = 0u;                     // 256 blocks x 64 = all NTOT rows
    float lg = logits[base + t];            // decoupled fast path for ALL rows
    float u = lg;
#pragma unroll
    for (int it = 0; it < 5; ++it) u = lg - sigm(u);
    out[base + t] = sigm(u);                // finale overwrites coupled rows
  }
  if (blockIdx.x == 0 && t == 0) *lctr = 0;

  // stage p tile: 64 d-rows x 64 points, coalesced uint4 (2 per thread)
#pragma unroll
  for (int k = 0; k < 2; ++k) {
    int idx = k * 512 + t;
    int r = idx >> 4, chunk = idx & 15;
    uint4 v = *(const uint4*)(pb + (size_t)r * NPTS + chunk * 4);
    *(uint4*)(sp + r * 64 + chunk * 4) = v;
  }
  __syncthreads();

  // GEMM1: t[n][e] = b1[e] + sum_d p[d][n]*W1[d][e]   (8 dims/wave)
  float tt[8];
#pragma unroll
  for (int j = 0; j < 8; ++j) tt[j] = b1[e0 + j];
#pragma unroll 8
  for (int d = 0; d < 64; ++d) {
    float pd = sp[d * 64 + lane];
#pragma unroll
    for (int j = 0; j < 8; ++j)
      tt[j] = fmaf(pd, W1[d * 64 + e0 + j], tt[j]);
  }
  // transpose t into LDS (separate buffer -> no race with sp readers)
#pragma unroll
  for (int j = 0; j < 8; ++j) st[lane * 65 + e0 + j] = tt[j];
  __syncthreads();

  // GEMM2: f[n][e] = b2[e] + sum_d t[n][d]*W2[d][e]
  float f[8];
#pragma unroll
  for (int j = 0; j < 8; ++j) f[j] = b2[e0 + j];
#pragma unroll 8
  for (int d = 0; d < 64; ++d) {
    float td = st[lane * 65 + d];
#pragma unroll
    for (int j = 0; j < 8; ++j)
      f[j] = fmaf(td, W2[d * 64 + e0 + j], f[j]);
  }

  float s = 0.f;
#pragma unroll
  for (int j = 0; j < 8; ++j) s = fmaf(f[j], f[j], s);
  sPart[w][lane] = s;
  __syncthreads();
  if (w == 0) {
    float s32 = (sPart[0][lane] + sPart[1][lane]) +
                (sPart[2][lane] + sPart[3][lane]);
    float s64 = s32 + ((sPart[4][lane] + sPart[5][lane]) +
                       (sPart[6][lane] + sPart[7][lane]));
    sq32[base + lane] = s32;
    sq[base + lane] = s64;
  }

  f32x4* o4 = (f32x4*)(f32f + (size_t)(base + lane) * 64 + e0);
#pragma unroll
  for (int jj = 0; jj < 2; ++jj) {
    f32x4 v; v[0] = f[4 * jj]; v[1] = f[4 * jj + 1]; v[2] = f[4 * jj + 2]; v[3] = f[4 * jj + 3];
    o4[jj] = v;
  }
  if (w < 4) {                               // dims 0..31 -> bf16 prefilter
    unsigned* ob = (unsigned*)(fpre + (size_t)(base + lane) * 32 + e0);
#pragma unroll
    for (int jj = 0; jj < 4; ++jj) {
      unsigned lo = f2bf(f[2 * jj]);
      unsigned hi = f2bf(f[2 * jj + 1]);
      ob[jj] = lo | (hi << 16);
    }
  }
}

// ---------------- K2: 32-dim prefilter Gram, triangle-symmetric (R2-validated) ----
// 1056 blocks = 2 x 528. Hot: per tile 1 ds_read + 4 MFMA (C = -0.5*sq_row) +
// max-tree margin test -> SGPR hitmask. Cold: only hit tiles. 1->2 cnt
// transition appends the row to the compact coupled list.
__global__ __launch_bounds__(256) void k2_gram_select(
    const unsigned short* __restrict__ fpre, // [NTOT][32]
    const float* __restrict__ sq32,          // [NTOT]
    unsigned* __restrict__ cnt,              // [NTOT]
    unsigned* __restrict__ cand,             // [NTOT][CAP]
    int* __restrict__ lctr,                  // coupled-list counter
    int* __restrict__ list) {                // [MAXM] coupled rows (global ids)
  __shared__ uint4 sB[1024];                 // 16 KB panel, XOR-swizzled
  int bid = blockIdx.x;
  int b = (bid >= 528) ? 1 : 0;
  int rem = bid - b * 528;
  int band = (int)((sqrtf(8.f * (float)rem + 1.f) - 1.f) * 0.5f);
  if (((band + 1) * (band + 2)) / 2 <= rem) band++;
  else if ((band * (band + 1)) / 2 > rem) band--;
  int seg = rem - (band * (band + 1)) / 2;

  int t = threadIdx.x;
  int lane = t & 63;
  int arow = lane & 15;
  int q = lane >> 4;
  int wave = t >> 6;
  int rowbase = band * 256 + wave * 64;
  int cbase = seg * 256;
  const unsigned short* fb = fpre + (size_t)b * NPTS * 32;
  const float* s32b = sq32 + b * NPTS;

  // ---- prologue: all global loads, then ONE barrier ----
  const uint4* gsrc = (const uint4*)fb + (size_t)seg * 1024;
  uint4 v[4];
#pragma unroll
  for (int k = 0; k < 4; ++k) v[k] = gsrc[t + k * 256];

  short8 afrag[4];
#pragma unroll
  for (int tr = 0; tr < 4; ++tr)
    afrag[tr] = *(const short8*)(fb + (size_t)(rowbase + tr * 16 + arow) * 32 + q * 8);

  f32x4 srq[4], nh[4];                       // nh = -0.5*sq_row -> MFMA C operand
#pragma unroll
  for (int tr = 0; tr < 4; ++tr) {
    srq[tr] = *(const f32x4*)(s32b + rowbase + tr * 16 + (q << 2));
    nh[tr] = -0.5f * srq[tr];
  }
  float thrc[16];                            // per-lane column threshold
#pragma unroll
  for (int cc = 0; cc < 4; ++cc)
#pragma unroll
    for (int tc = 0; tc < 4; ++tc)
      thrc[cc * 4 + tc] = 0.5f * s32b[cbase + cc * 64 + tc * 16 + arow] - 0.5f * MARG;

#pragma unroll
  for (int k = 0; k < 4; ++k) {
    int c = t + k * 256;
    int r = c >> 2, qq = c & 3;
    sB[r * 4 + (qq ^ (r & 3))] = v[k];
  }
  __syncthreads();   // the ONLY barrier

  // ---- hot pass: MFMA (acc = a - 0.5*sq_row) + max-tree margin test ----
  unsigned hitmask = 0u;
#pragma unroll
  for (int cc = 0; cc < 4; ++cc)
#pragma unroll
    for (int tc = 0; tc < 4; ++tc) {
      int e = cc * 4 + tc;
      int rl = cc * 64 + tc * 16 + arow;
      short8 bf = *(const short8*)&sB[rl * 4 + (q ^ (rl & 3))];
      f32x4 a0 = __builtin_amdgcn_mfma_f32_16x16x32_bf16(afrag[0], bf, nh[0], 0, 0, 0);
      f32x4 a1 = __builtin_amdgcn_mfma_f32_16x16x32_bf16(afrag[1], bf, nh[1], 0, 0, 0);
      f32x4 a2 = __builtin_amdgcn_mfma_f32_16x16x32_bf16(afrag[2], bf, nh[2], 0, 0, 0);
      f32x4 a3 = __builtin_amdgcn_mfma_f32_16x16x32_bf16(afrag[3], bf, nh[3], 0, 0, 0);
      float m0 = fmaxf(fmaxf(a0[0], a0[1]), fmaxf(a0[2], a0[3]));
      float m1 = fmaxf(fmaxf(a1[0], a1[1]), fmaxf(a1[2], a1[3]));
      float m2 = fmaxf(fmaxf(a2[0], a2[1]), fmaxf(a2[2], a2[3]));
      float m3 = fmaxf(fmaxf(a3[0], a3[1]), fmaxf(a3[2], a3[3]));
      float m = fmaxf(fmaxf(m0, m1), fmaxf(m2, m3));
      if (__ballot(m > thrc[e])) hitmask |= (1u << e);
    }

  // ---- cold: only hit tiles ----
  if (hitmask) {
#pragma unroll 1
    for (int e = 0; e < 16; ++e) {
      if (!(hitmask & (1u << e))) continue;
      int cc = e >> 2, tc = e & 3;
      int rl = cc * 64 + tc * 16 + arow;
      short8 bf = *(const short8*)&sB[rl * 4 + (q ^ (rl & 3))];
      int colpt = cbase + cc * 64 + tc * 16 + arow;
      float scv = s32b[colpt];
      f32x4 acc[4];
#pragma unroll
      for (int tr = 0; tr < 4; ++tr)
        acc[tr] = __builtin_amdgcn_mfma_f32_16x16x32_bf16(afrag[tr], bf, nh[tr], 0, 0, 0);
#pragma unroll
      for (int tr = 0; tr < 4; ++tr)
#pragma unroll
        for (int rg = 0; rg < 4; ++rg) {
          float d2 = scv - 2.f * acc[tr][rg];      // = sq_row + sq_col - 2*dot
          if (d2 < MARG) {
            int rowpt = rowbase + tr * 16 + (q << 2) + rg;
            int gr = b * NPTS + rowpt;
            union { float f; unsigned u; } cv; cv.f = d2 + 16.f;  // monotone bits
            unsigned kb = cv.u & 0xFFFFE000u;
            unsigned slot = atomicAdd(&cnt[gr], 1u);
            if (slot < CAP) cand[gr * CAP + slot] = kb | (unsigned)colpt;
            if (slot == 1u) {                 // 1->2 transition: row becomes coupled
              int ls = atomicAdd(lctr, 1);
              if (ls < MAXM) list[ls] = gr;
            }
            if (band != seg) {
              int gc = b * NPTS + colpt;
              unsigned slot2 = atomicAdd(&cnt[gc], 1u);
              if (slot2 < CAP) cand[gc * CAP + slot2] = kb | (unsigned)rowpt;
              if (slot2 == 1u) {
                int ls2 = atomicAdd(lctr, 1);
                if (ls2 < MAXM) list[ls2] = gc;
              }
            }
          }
        }
    }
  }
}

// ---------------- K3C: coupled subgraph only (1 block x 512) ----------------
// Decoupled rows already written by k1. Slot-compact state in LDS (24 KB).
// Kernel boundary provides coherence -> plain loads (R2-validated pattern).
__global__ __launch_bounds__(512) void k3c(
    const float* __restrict__ f32f, const float* __restrict__ sq,
    const unsigned* __restrict__ cnt, const unsigned* __restrict__ cand,
    const int* __restrict__ lctr, const int* __restrict__ list,
    int* __restrict__ rowmap, float* __restrict__ Wbuf, int* __restrict__ IDXs,
    const float* __restrict__ logits, float* __restrict__ out) {
  __shared__ float qs[QMAX];                // 8 KB (slot-indexed)
  __shared__ float su[QMAX];                // 8 KB
  __shared__ int sl[QMAX];                  // 8 KB
  int t = threadIdx.x;
  int nm = *lctr; if (nm > QMAX) nm = QMAX;

#pragma unroll 1
  for (int k = t; k < nm; k += 512) {
    int r = list[k];
    sl[k] = r;
    rowmap[r] = k;                          // every captured neighbor is coupled
    qs[k] = sigm(logits[r]);
  }
  __syncthreads();

  // build slot-indexed W/IDX
#pragma unroll 1
  for (int k = t; k < nm; k += 512) {
    int r = sl[k];
    int b = r >> 13;
    unsigned count = cnt[r];
    if (count > CAP) count = CAP;

    unsigned kc[CAP];
#pragma unroll
    for (int j = 0; j < CAP; ++j)
      kc[j] = (j < (int)count) ? cand[r * CAP + j] : 0xFFFFFFFFu;
#pragma unroll
    for (int a = 0; a < CAP - 1; ++a)
#pragma unroll
      for (int c = 0; c < CAP - 1; ++c) {
        unsigned lo = min(kc[c], kc[c + 1]);
        unsigned hi = max(kc[c], kc[c + 1]);
        kc[c] = lo; kc[c + 1] = hi;
      }

    float fr[64];
    const f32x4* fr4 = (const f32x4*)(f32f + (size_t)r * 64);
#pragma unroll
    for (int j = 0; j < 16; ++j) {
      f32x4 v = fr4[j];
      fr[4 * j] = v[0]; fr[4 * j + 1] = v[1]; fr[4 * j + 2] = v[2]; fr[4 * j + 3] = v[3];
    }
    float sqr = sq[r];
    int nsel = (int)count < KNB ? (int)count : KNB;
#pragma unroll
    for (int kk = 0; kk < KNB; ++kk) {
      float wgt = 0.f;
      int gi = r;
      if (kk < nsel) {
        int col = (int)(kc[kk] & 8191u);
        gi = b * NPTS + col;
        const float* fm = f32f + (size_t)gi * 64;
        float dot = 0.f;
#pragma unroll
        for (int d = 0; d < 64; ++d) dot = fmaf(fr[d], fm[d], dot); // matches sq chain
        float d2 = sqr + sq[gi] - 2.f * dot;
        wgt = expf(-d2);
      }
      Wbuf[k * KNB + kk] = wgt;
      IDXs[k * KNB + kk] = rowmap[gi] & (QMAX - 1);  // cheap OOB insurance
    }
  }
  __syncthreads();                          // Wbuf/IDXs visible block-wide

  for (int it = 0; it < 5; ++it) {
#pragma unroll 1
    for (int k = t; k < nm; k += 512) {
      float msg = 0.f;
      const float* wp = Wbuf + k * KNB;
      const int* ip = IDXs + k * KNB;
#pragma unroll
      for (int kk = 0; kk < KNB; ++kk) msg = fmaf(wp[kk], qs[ip[kk]], msg);
      su[k] = logits[sl[k]] - msg;
    }
    __syncthreads();
#pragma unroll 1
    for (int k = t; k < nm; k += 512) qs[k] = sigm(su[k]);
    __syncthreads();
  }
#pragma unroll 1
  for (int k = t; k < nm; k += 512) out[sl[k]] = sigm(su[k]);
}

// ---------------- launch ----------------
extern "C" void kernel_launch(void* const* d_in, const int* in_sizes, int n_in,
                              void* d_out, int out_size, void* d_ws, size_t ws_size,
                              hipStream_t stream) {
  const float* logits = (const float*)d_in[0]; // [2][8192]
  const float* p      = (const float*)d_in[1]; // [2][64][8192]
  const float* W1     = (const float*)d_in[2];
  const float* b1     = (const float*)d_in[3];
  const float* W2     = (const float*)d_in[4];
  const float* b2     = (const float*)d_in[5];
  float* out = (float*)d_out;                  // [2][8192]

  char* ws = (char*)d_ws;
  float* f32f = (float*)ws;                                        // NTOT*64 f
  unsigned short* fpre = (unsigned short*)(f32f + (size_t)NTOT * 64); // NTOT*32 bf16
  float* sq = (float*)(fpre + (size_t)NTOT * 32);                  // NTOT f
  float* sq32 = sq + NTOT;                                         // NTOT f
  unsigned* cnt = (unsigned*)(sq32 + NTOT);                        // NTOT u32
  unsigned* cand = cnt + NTOT;                                     // NTOT*CAP u32
  int* lctr = (int*)(cand + (size_t)NTOT * CAP);                   // 1 i32
  int* list = lctr + 1;                                            // MAXM i32
  int* rowmap = list + MAXM;                                       // NTOT i32
  float* Wbuf = (float*)(rowmap + NTOT);                           // QMAX*KNB f
  int* IDXs = (int*)(Wbuf + (size_t)QMAX * KNB);                   // QMAX*KNB i32

  k1_encode<<<256, 512, 0, stream>>>(p, W1, b1, W2, b2, logits, out,
                                     f32f, fpre, sq, sq32, cnt, lctr);
  k2_gram_select<<<1056, 256, 0, stream>>>(fpre, sq32, cnt, cand, lctr, list);
  k3c<<<1, 512, 0, stream>>>(f32f, sq, cnt, cand, lctr, list,
                             rowmap, Wbuf, IDXs, logits, out);
}